// Round 2
// baseline (342.677 us; speedup 1.0000x reference)
//
#include <hip/hip_runtime.h>
#include <math.h>

#define CC 256      // channels
#define HW 65536    // 256*256 pixels
#define SS 256      // pooled spatial (16*16)

// ws layout (float offsets)
#define WS_XT   0        // Xt[s][c]  (pooled sup_x, TRANSPOSED) 256*256
#define WS_XN   65536    // Xn[c][s]                             256*256
#define WS_YG   131072   // pooled sup_y [256]
#define WS_INVN 131328   // 1/max(||Xn[:,n]||,1e-4)  [256]
#define WS_SELF 131584   // sel flag as float        [256]

// ---------------------------------------------------------------- pooling
// blocks 0..255: channel c of sup_x -> Xt[0..255][c]
// block 256:     sup_y -> yg[0..255]
__global__ void pool_kernel(const float* __restrict__ sup_x,
                            const float* __restrict__ sup_y,
                            float* __restrict__ ws) {
    int blk = blockIdx.x;
    int t   = threadIdx.x;                 // column w = t
    const float* src = (blk < CC) ? (sup_x + (size_t)blk * HW) : sup_y;

    for (int py = 0; py < 16; ++py) {
        float acc = 0.f;
        int hbase = py * 16;
        #pragma unroll
        for (int i = 0; i < 16; ++i)
            acc += src[(hbase + i) * 256 + t];   // coalesced rows
        // sum over the 16 columns of one pooled cell (16-lane groups)
        acc += __shfl_down(acc, 8, 16);
        acc += __shfl_down(acc, 4, 16);
        acc += __shfl_down(acc, 2, 16);
        acc += __shfl_down(acc, 1, 16);
        if ((t & 15) == 0) {
            int cell = py * 16 + (t >> 4);
            float v = acc * (1.f / 256.f);
            if (blk < CC) ws[WS_XT + cell * SS + blk] = v;  // transposed store
            else          ws[WS_YG + cell] = v;
        }
    }
}

// ---------------------------------------------------- gram + softmax + Xn
// block i: w1 row i -> softmax -> tridiag T row -> Xn[i][:]
// All bulk reads go through Xt so the dot loop is lane-coalesced.
__global__ void calib_kernel(const float* __restrict__ cal,
                             float* __restrict__ ws) {
    int i = blockIdx.x;
    int j = threadIdx.x;
    const float* Xt = ws + WS_XT;
    float* Xn = ws + WS_XN;

    __shared__ float xi[SS];
    __shared__ float e[CC];
    __shared__ float red[256];
    __shared__ float T[3];

    xi[j] = Xt[j * SS + i];   // column i of Xt = row i of X (one-time, uncoalesced ok)
    __syncthreads();

    // w1[i][j] = X[i,:] . X[j,:] = sum_s xi[s] * Xt[s][j]   (coalesced in j)
    float dot = 0.f;
    #pragma unroll 4
    for (int s = 0; s < SS; ++s) dot += xi[s] * Xt[s * SS + j];

    // row max
    red[j] = dot; __syncthreads();
    for (int off = 128; off > 0; off >>= 1) {
        if (j < off) red[j] = fmaxf(red[j], red[j + off]);
        __syncthreads();
    }
    float m = red[0];
    __syncthreads();

    float ev = expf(dot - m);
    e[j] = ev;
    red[j] = ev; __syncthreads();
    for (int off = 128; off > 0; off >>= 1) {
        if (j < off) red[j] += red[j + off];
        __syncthreads();
    }
    float esum = red[0];
    __syncthreads();

    if (j < 3) {
        int jj = i + j - 1;
        float tv = 0.f;
        if (jj >= 0 && jj < CC) {
            float soft = e[jj] / esum;
            tv = (1.f + 0.2f * soft) * cal[i * CC + jj];
        }
        T[j] = tv;
    }
    __syncthreads();

    float v = T[1] * xi[j];
    if (i > 0)      v += T[0] * Xt[j * SS + i - 1];
    if (i < CC - 1) v += T[2] * Xt[j * SS + i + 1];
    Xn[i * SS + j] = v;   // coalesced
}

// ------------------------------------------------ proto inv-norms + sel
__global__ void prep_kernel(float* __restrict__ ws) {
    int n = threadIdx.x;
    const float* Xn = ws + WS_XN;
    float s = 0.f;
    #pragma unroll 4
    for (int c = 0; c < CC; ++c) {     // coalesced per c-row
        float v = Xn[c * SS + n];
        s += v * v;
    }
    ws[WS_INVN + n] = 1.f / fmaxf(sqrtf(s), 1e-4f);
    float g = ws[WS_YG + n];
    ws[WS_SELF + n] = (g > 0.5f) ? 1.f : 0.f;
}

// ------------------------------------- fused GEMM + softmax + argmax
// Block: 128 pixels x 256 protos. 256 threads, each 8 px x 16 protos.
// tn = tid&15 -> proto group (protos n = tn*4 + 64g + e, g,e in 0..3)
// tm = tid>>4 -> pixel group (pixels p = tm*8 + i)
// K staged in LDS chunks of 16. No dists tile in LDS: softmax/argmax
// reductions done from registers with small [128][17] partial buffers.
#define MB 128
#define KC 16

__global__ __launch_bounds__(256, 2)
void main_kernel(const float* __restrict__ qry,
                 const float* __restrict__ ws,
                 float* __restrict__ out) {
    __shared__ float smem[KC * MB + KC * 256];   // qs [16][128] | bs [16][256] = 6144 floats
    __shared__ float invn_s[256];
    __shared__ float self_s[256];
    __shared__ float qred[256];
    __shared__ float invq_s[MB];
    __shared__ float mfin[MB];
    __shared__ float afin[MB];

    int tid = threadIdx.x;
    int tn = tid & 15;        // proto group
    int tm = tid >> 4;        // pixel group
    int p0 = blockIdx.x * MB;
    const float* Xn = ws + WS_XN;
    float* qs = smem;               // [KC][128]
    float* bs = smem + KC * MB;     // [KC][256]

    invn_s[tid] = ws[WS_INVN + tid];
    self_s[tid] = ws[WS_SELF + tid];

    float acc[8][16];
    #pragma unroll
    for (int i = 0; i < 8; ++i)
        #pragma unroll
        for (int j = 0; j < 16; ++j) acc[i][j] = 0.f;

    float qpart = 0.f;   // partial ||q||^2 for pixel (tid & 127)

    for (int k0 = 0; k0 < CC; k0 += KC) {
        __syncthreads();
        // stage qry chunk [KC][128]  (coalesced; p = tid&127 fixed per thread)
        #pragma unroll
        for (int u = 0; u < 8; ++u) {
            int e2 = tid + 256 * u;
            int kk = e2 >> 7, p = e2 & 127;
            float v = qry[(size_t)(k0 + kk) * HW + p0 + p];
            qs[kk * MB + p] = v;
            qpart += v * v;
        }
        // stage Xn chunk [KC][256] (coalesced, L2-resident)
        #pragma unroll
        for (int u = 0; u < KC; ++u)
            bs[u * 256 + tid] = Xn[(k0 + u) * SS + tid];
        __syncthreads();

        #pragma unroll
        for (int kk = 0; kk < KC; ++kk) {
            // q: 4 distinct addrs/wave, stride 32B -> conflict-free broadcast
            float4 qa = *reinterpret_cast<const float4*>(&qs[kk * MB + tm * 8]);
            float4 qb = *reinterpret_cast<const float4*>(&qs[kk * MB + tm * 8 + 4]);
            // b: 16 consecutive float4s/wave per read -> 2-way (free)
            float4 b0 = *reinterpret_cast<const float4*>(&bs[kk * 256 + tn * 4]);
            float4 b1 = *reinterpret_cast<const float4*>(&bs[kk * 256 + tn * 4 + 64]);
            float4 b2 = *reinterpret_cast<const float4*>(&bs[kk * 256 + tn * 4 + 128]);
            float4 b3 = *reinterpret_cast<const float4*>(&bs[kk * 256 + tn * 4 + 192]);
            float q8[8]  = {qa.x, qa.y, qa.z, qa.w, qb.x, qb.y, qb.z, qb.w};
            float b16[16] = {b0.x, b0.y, b0.z, b0.w, b1.x, b1.y, b1.z, b1.w,
                             b2.x, b2.y, b2.z, b2.w, b3.x, b3.y, b3.z, b3.w};
            #pragma unroll
            for (int i = 0; i < 8; ++i)
                #pragma unroll
                for (int j = 0; j < 16; ++j)
                    acc[i][j] += q8[i] * b16[j];
        }
    }

    // per-pixel ||q||^2: partials in threads p and p+128
    qred[tid] = qpart;
    __syncthreads();
    if (tid < MB) {
        float s = qred[tid] + qred[tid + MB];
        invq_s[tid] = 1.f / fmaxf(sqrtf(s), 1e-4f);
    }
    __syncthreads();

    // ---- phase A: scale+mask in-register, thread-local max/argmax
    float* rmax = smem;          // [128][17]
    float* rarg = smem + 2176;   // [128][17]
    #pragma unroll
    for (int i = 0; i < 8; ++i) {
        int p = tm * 8 + i;
        float iq = invq_s[p] * 20.f;
        float bv = -3.4e38f;
        int   ba = 0;
        #pragma unroll
        for (int j = 0; j < 16; ++j) {
            int n = ((j >> 2) << 6) + tn * 4 + (j & 3);   // ascending in j
            float d = acc[i][j] * invn_s[n] * iq;
            d = (self_s[n] > 0.5f) ? d : -1e9f;
            acc[i][j] = d;
            if (d > bv) { bv = d; ba = n; }               // strict > keeps lowest n
        }
        rmax[p * 17 + tn] = bv;
        rarg[p * 17 + tn] = (float)ba;
    }
    __syncthreads();

    // reduce 16 partials/pixel: 2 threads per pixel + shfl
    {
        int p = tid >> 1, h = tid & 1;
        float bv = -3.4e38f, ba = 1e9f;
        #pragma unroll
        for (int jj = 0; jj < 8; ++jj) {
            int t2 = h * 8 + jj;
            float v = rmax[p * 17 + t2];
            float a = rarg[p * 17 + t2];
            if (v > bv || (v == bv && a < ba)) { bv = v; ba = a; }
        }
        float ov = __shfl_xor(bv, 1);
        float oa = __shfl_xor(ba, 1);
        if (ov > bv || (ov == bv && oa < ba)) { bv = ov; ba = oa; }
        if (h == 0) { mfin[p] = bv; afin[p] = ba; }
    }
    __syncthreads();

    // ---- phase B: exp-sums from registers
    float* s1a = smem;           // [128][17]
    float* s2a = smem + 2176;    // [128][17]
    #pragma unroll
    for (int i = 0; i < 8; ++i) {
        int p = tm * 8 + i;
        float m = mfin[p];
        float s1 = 0.f, s2 = 0.f;
        #pragma unroll
        for (int j = 0; j < 16; ++j) {
            float v = acc[i][j];
            float ev = expf(v - m);    // masked -1e9 -> 0
            s1 += ev;
            s2 += ev * v;
        }
        s1a[p * 17 + tn] = s1;
        s2a[p * 17 + tn] = s2;
    }
    __syncthreads();

    {
        int p = tid >> 1, h = tid & 1;
        float s1 = 0.f, s2 = 0.f;
        #pragma unroll
        for (int jj = 0; jj < 8; ++jj) {
            int t2 = h * 8 + jj;
            s1 += s1a[p * 17 + t2];
            s2 += s2a[p * 17 + t2];
        }
        s1 += __shfl_xor(s1, 1);
        s2 += __shfl_xor(s2, 1);
        if (h == 0) {
            out[p0 + p]      = s2 / s1;    // pred_grid
            out[HW + p0 + p] = afin[p];    // debug_assign
        }
    }
}

// ----------------------------------------------------------------- launch
extern "C" void kernel_launch(void* const* d_in, const int* in_sizes, int n_in,
                              void* d_out, int out_size, void* d_ws, size_t ws_size,
                              hipStream_t stream) {
    const float* qry   = (const float*)d_in[0];
    const float* sup_x = (const float*)d_in[1];
    const float* sup_y = (const float*)d_in[2];
    // d_in[3] = s_init_seed (unused by reference)
    const float* cal   = (const float*)d_in[4];
    float* out = (float*)d_out;
    float* ws  = (float*)d_ws;

    pool_kernel<<<257, 256, 0, stream>>>(sup_x, sup_y, ws);
    calib_kernel<<<256, 256, 0, stream>>>(cal, ws);
    prep_kernel<<<1, 256, 0, stream>>>(ws);
    main_kernel<<<HW / MB, 256, 0, stream>>>(qry, ws, out);
}